// Round 1
// baseline (1327.634 us; speedup 1.0000x reference)
//
#include <hip/hip_runtime.h>
#include <stdint.h>

#define EMB 64
#define BN_EPS 1e-5f

// ---------------- zero init (ws is poisoned 0xAA every call) ----------------
__global__ void k_zero(int* __restrict__ counts, float* __restrict__ stats,
                       int n, int nstats) {
    int i = blockIdx.x * blockDim.x + threadIdx.x;
    if (i < n) counts[i] = 0;
    if (i < nstats) stats[i] = 0.0f;
}

// ---------------- CSR build ----------------
__global__ void k_hist(const int* __restrict__ ei, int* __restrict__ counts, int E) {
    int stride = gridDim.x * blockDim.x;
    for (int e = blockIdx.x * blockDim.x + threadIdx.x; e < E; e += stride) {
        atomicAdd(&counts[ei[E + e]], 1);   // dst row
    }
}

__global__ void k_scanA(const int* __restrict__ counts, int* __restrict__ bsum, int n) {
    __shared__ int a[256];
    int t = threadIdx.x;
    int i = blockIdx.x * 256 + t;
    a[t] = (i < n) ? counts[i] : 0;
    __syncthreads();
    for (int off = 128; off >= 1; off >>= 1) {
        if (t < off) a[t] += a[t + off];
        __syncthreads();
    }
    if (t == 0) bsum[blockIdx.x] = a[0];
}

__global__ void k_scanB(int* __restrict__ bsum, int nb) {
    __shared__ int a[256];
    __shared__ int carry;
    int t = threadIdx.x;
    if (t == 0) carry = 0;
    __syncthreads();
    for (int base = 0; base < nb; base += 256) {
        int v = (base + t < nb) ? bsum[base + t] : 0;
        a[t] = v;
        __syncthreads();
        for (int off = 1; off < 256; off <<= 1) {
            int x = (t >= off) ? a[t - off] : 0;
            __syncthreads();
            a[t] += x;
            __syncthreads();
        }
        int excl = carry + (t ? a[t - 1] : 0);
        int tot  = carry + a[255];
        if (base + t < nb) bsum[base + t] = excl;   // in place: becomes block offsets
        __syncthreads();
        if (t == 0) carry = tot;
        __syncthreads();
    }
}

__global__ void k_scanC(const int* __restrict__ counts, const int* __restrict__ boff,
                        int* __restrict__ rowst, int* __restrict__ cursor, int n) {
    __shared__ int a[256];
    int t = threadIdx.x;
    int i = blockIdx.x * 256 + t;
    int v = (i < n) ? counts[i] : 0;
    a[t] = v;
    __syncthreads();
    for (int off = 1; off < 256; off <<= 1) {
        int x = (t >= off) ? a[t - off] : 0;
        __syncthreads();
        a[t] += x;
        __syncthreads();
    }
    int excl = boff[blockIdx.x] + (t ? a[t - 1] : 0);
    if (i < n) { rowst[i] = excl; cursor[i] = excl; }
}

__global__ void k_scatter(const int* __restrict__ ei, const float* __restrict__ ew,
                          int* __restrict__ cursor, int2* __restrict__ pairs, int E) {
    int stride = gridDim.x * blockDim.x;
    for (int e = blockIdx.x * blockDim.x + threadIdx.x; e < E; e += stride) {
        int d = ei[E + e];
        int pos = atomicAdd(&cursor[d], 1);
        pairs[pos] = make_int2(ei[e], __float_as_int(ew[e]));
    }
}

// ---------------- aggregation: wave-per-node, lane=feature ----------------
__global__ void k_agg(const float* __restrict__ h, const int* __restrict__ rowst,
                      const int* __restrict__ counts, const int2* __restrict__ pairs,
                      float* __restrict__ out, int N) {
    const int lane = threadIdx.x & 63;
    int wave = (blockIdx.x * blockDim.x + threadIdx.x) >> 6;
    const int nwaves = (gridDim.x * blockDim.x) >> 6;
    for (int node = wave; node < N; node += nwaves) {
        int un = __builtin_amdgcn_readfirstlane(node);
        int s = rowst[un];
        int c = counts[un];
        int end = s + c;
        float a0 = 0.f, a1 = 0.f, a2 = 0.f, a3 = 0.f;
        int e = s;
        for (; e + 3 < end; e += 4) {
            int2 p0 = pairs[e];
            int2 p1 = pairs[e + 1];
            int2 p2 = pairs[e + 2];
            int2 p3 = pairs[e + 3];
            float v0 = h[(size_t)p0.x * EMB + lane];
            float v1 = h[(size_t)p1.x * EMB + lane];
            float v2 = h[(size_t)p2.x * EMB + lane];
            float v3 = h[(size_t)p3.x * EMB + lane];
            a0 = fmaf(__int_as_float(p0.y), v0, a0);
            a1 = fmaf(__int_as_float(p1.y), v1, a1);
            a2 = fmaf(__int_as_float(p2.y), v2, a2);
            a3 = fmaf(__int_as_float(p3.y), v3, a3);
        }
        for (; e < end; e++) {
            int2 p0 = pairs[e];
            a0 = fmaf(__int_as_float(p0.y), h[(size_t)p0.x * EMB + lane], a0);
        }
        out[(size_t)un * EMB + lane] = ((a0 + a1) + (a2 + a3)) + h[(size_t)un * EMB + lane];
    }
}

// ---------------- matmul: wave handles 64 nodes x 32 cols; W via s_loads ----
// BN_IN: apply batchnorm(stats)+relu to the input row before the matmul.
template <bool BN_IN>
__global__ void k_mm(const float* __restrict__ in, const float* __restrict__ W,
                     const float* __restrict__ bias, const float* __restrict__ stats,
                     const float* __restrict__ g, const float* __restrict__ be,
                     float invN, float* __restrict__ out, int N) {
    const int lane = threadIdx.x & 63;
    int wv = (blockIdx.x * blockDim.x + threadIdx.x) >> 6;
    const int nwv = (gridDim.x * blockDim.x) >> 6;
    const int ntiles = ((N + 63) >> 6) * 2;
    for (int tile = wv; tile < ntiles; tile += nwv) {
        int utile = __builtin_amdgcn_readfirstlane(tile);
        int half = utile & 1;                 // uniform
        int node = (utile >> 1) * 64 + lane;  // consecutive nodes across lanes
        bool valid = node < N;

        float row[EMB];
        if (valid) {
            const float4* in4 = (const float4*)(in + (size_t)node * EMB);
#pragma unroll
            for (int i = 0; i < 16; i++) {
                float4 v = in4[i];
                row[4 * i + 0] = v.x; row[4 * i + 1] = v.y;
                row[4 * i + 2] = v.z; row[4 * i + 3] = v.w;
            }
        } else {
#pragma unroll
            for (int i = 0; i < EMB; i++) row[i] = 0.f;
        }

        if (BN_IN) {
#pragma unroll
            for (int f = 0; f < EMB; f++) {
                float m  = stats[f] * invN;
                float va = fmaf(stats[EMB + f], invN, -m * m);
                float rs = rsqrtf(va + BN_EPS);
                float sc = rs * g[f];
                float sh = fmaf(-m, sc, be[f]);
                row[f] = fmaxf(0.f, fmaf(row[f], sc, sh));
            }
        }

        int jbase = half * 32;
        for (int jc = 0; jc < 4; jc++) {
            int j0 = jbase + jc * 8;   // uniform
            float acc[8];
#pragma unroll
            for (int k = 0; k < 8; k++) acc[k] = bias[j0 + k];
#pragma unroll
            for (int f = 0; f < EMB; f++) {
                const float* wr = W + f * EMB + j0;   // uniform -> s_load
#pragma unroll
                for (int k = 0; k < 8; k++) acc[k] = fmaf(row[f], wr[k], acc[k]);
            }
            if (valid) {
                float4* o4 = (float4*)(out + (size_t)node * EMB + j0);
                o4[0] = make_float4(acc[0], acc[1], acc[2], acc[3]);
                o4[1] = make_float4(acc[4], acc[5], acc[6], acc[7]);
            }
        }
    }
}

// ---------------- per-feature sum / sumsq ----------------
__global__ void k_stats(const float* __restrict__ in, float* __restrict__ st, int total) {
    float s = 0.f, q = 0.f;
    int stride = gridDim.x * blockDim.x;
    for (int i = blockIdx.x * blockDim.x + threadIdx.x; i < total; i += stride) {
        float v = in[i];
        s += v;
        q = fmaf(v, v, q);
    }
    __shared__ float rs[256], rq[256];
    rs[threadIdx.x] = s; rq[threadIdx.x] = q;
    __syncthreads();
    if (threadIdx.x < 64) {
#pragma unroll
        for (int w = 64; w < 256; w += 64) {
            s += rs[threadIdx.x + w];
            q += rq[threadIdx.x + w];
        }
        atomicAdd(&st[threadIdx.x], s);
        atomicAdd(&st[EMB + threadIdx.x], q);
    }
}

// ---------------- outer BN + relu + residual ----------------
__global__ void k_bnres(const float* __restrict__ u, const float* __restrict__ st,
                        const float* __restrict__ g, const float* __restrict__ be,
                        const float* __restrict__ hin, float* __restrict__ hout,
                        float invN, int total4) {
    int stride = gridDim.x * blockDim.x;
    for (int i4 = blockIdx.x * blockDim.x + threadIdx.x; i4 < total4; i4 += stride) {
        int c = i4 & 15;  // which float4-chunk of the 64-feature row
        float4 uv = ((const float4*)u)[i4];
        float4 hv = ((const float4*)hin)[i4];
        float4 sv = ((const float4*)st)[c];
        float4 qv = ((const float4*)(st + EMB))[c];
        float4 gv = ((const float4*)g)[c];
        float4 bv = ((const float4*)be)[c];
        float4 o;
#define BNR(comp)                                                     \
        {                                                             \
            float m  = sv.comp * invN;                                \
            float va = fmaf(qv.comp, invN, -m * m);                   \
            float rs = rsqrtf(va + BN_EPS);                           \
            float sc = rs * gv.comp;                                  \
            float sh = fmaf(-m, sc, bv.comp);                         \
            float r  = fmaxf(0.f, fmaf(uv.comp, sc, sh));             \
            o.comp = r + hv.comp;                                     \
        }
        BNR(x) BNR(y) BNR(z) BNR(w)
#undef BNR
        ((float4*)hout)[i4] = o;
    }
}

// ---------------- launcher ----------------
extern "C" void kernel_launch(void* const* d_in, const int* in_sizes, int n_in,
                              void* d_out, int out_size, void* d_ws, size_t ws_size,
                              hipStream_t stream) {
    const float* x     = (const float*)d_in[0];
    const int*   ei    = (const int*)d_in[1];
    const float* ew    = (const float*)d_in[3];
    const float* ae_w  = (const float*)d_in[4];
    const float* ae_b  = (const float*)d_in[5];
    const float* W1    = (const float*)d_in[6];
    const float* b1    = (const float*)d_in[7];
    const float* g1    = (const float*)d_in[8];
    const float* be1   = (const float*)d_in[9];
    const float* W2    = (const float*)d_in[10];
    const float* b2    = (const float*)d_in[11];
    const float* g_out = (const float*)d_in[12];
    const float* be_out= (const float*)d_in[13];

    const int N = in_sizes[0] / EMB;      // x is [N,1,64]
    const int E = in_sizes[3];            // edge_weight [E]
    const int L = in_sizes[6] / (EMB * EMB);
    const float invN = 1.0f / (float)N;

    // workspace carve (256B aligned)
    uintptr_t p = (uintptr_t)d_ws;
    auto alloc = [&](size_t bytes) -> void* {
        p = (p + 255) & ~(uintptr_t)255;
        void* r = (void*)p;
        p += bytes;
        return r;
    };
    float* h     = (float*)alloc((size_t)N * EMB * 4);
    float* bufa  = (float*)alloc((size_t)N * EMB * 4);  // agg output, then reused as u
    float* buft  = (float*)alloc((size_t)N * EMB * 4);  // t
    int*   counts= (int*)alloc((size_t)N * 4);
    int*   rowst = (int*)alloc((size_t)N * 4);
    int*   cursor= (int*)alloc((size_t)N * 4);
    const int NB = (N + 255) / 256;
    int*   bsum  = (int*)alloc((size_t)NB * 4);
    int2*  pairs = (int2*)alloc((size_t)E * 8);
    float* stats = (float*)alloc((size_t)L * 2 * 2 * EMB * 4);
    (void)ws_size; (void)n_in; (void)out_size;

    const int nstats = L * 2 * 2 * EMB;
    int zgrid = ((N > nstats ? N : nstats) + 255) / 256;
    hipLaunchKernelGGL(k_zero, dim3(zgrid), dim3(256), 0, stream, counts, stats, N, nstats);

    // encoder: h = x @ ae_w + ae_b
    const int ntiles = ((N + 63) / 64) * 2;
    const int mmgrid = (ntiles + 3) / 4;   // 4 waves / block
    hipLaunchKernelGGL(k_mm<false>, dim3(mmgrid), dim3(256), 0, stream,
                       x, ae_w, ae_b, (const float*)nullptr, (const float*)nullptr,
                       (const float*)nullptr, 0.f, h, N);

    // CSR build
    const int eg = (E + 255) / 256;
    hipLaunchKernelGGL(k_hist,  dim3(eg), dim3(256), 0, stream, ei, counts, E);
    hipLaunchKernelGGL(k_scanA, dim3(NB), dim3(256), 0, stream, counts, bsum, N);
    hipLaunchKernelGGL(k_scanB, dim3(1),  dim3(256), 0, stream, bsum, NB);
    hipLaunchKernelGGL(k_scanC, dim3(NB), dim3(256), 0, stream, counts, bsum, rowst, cursor, N);
    hipLaunchKernelGGL(k_scatter, dim3(eg), dim3(256), 0, stream, ei, ew, cursor, pairs, E);

    for (int l = 0; l < L; l++) {
        const float* stats1 = stats + (size_t)(l * 2 + 0) * 2 * EMB;
        const float* stats2 = stats + (size_t)(l * 2 + 1) * 2 * EMB;

        // agg + self
        hipLaunchKernelGGL(k_agg, dim3(1024), dim3(256), 0, stream,
                           h, rowst, counts, pairs, bufa, N);
        // t = (agg) @ W1 + b1
        hipLaunchKernelGGL(k_mm<false>, dim3(mmgrid), dim3(256), 0, stream,
                           bufa, W1 + (size_t)l * EMB * EMB, b1 + (size_t)l * EMB,
                           (const float*)nullptr, (const float*)nullptr,
                           (const float*)nullptr, 0.f, buft, N);
        // stats of t
        hipLaunchKernelGGL(k_stats, dim3(256), dim3(256), 0, stream,
                           buft, (float*)stats1, N * EMB);
        // u = relu(bn(t)) @ W2 + b2     (bufa reused as u)
        hipLaunchKernelGGL(k_mm<true>, dim3(mmgrid), dim3(256), 0, stream,
                           buft, W2 + (size_t)l * EMB * EMB, b2 + (size_t)l * EMB,
                           stats1, g1 + (size_t)l * EMB, be1 + (size_t)l * EMB,
                           invN, bufa, N);
        // stats of u
        hipLaunchKernelGGL(k_stats, dim3(256), dim3(256), 0, stream,
                           bufa, (float*)stats2, N * EMB);
        // h = relu(bn(u)) + h   (last layer writes d_out)
        float* hout = (l == L - 1) ? (float*)d_out : h;
        hipLaunchKernelGGL(k_bnres, dim3(1024), dim3(256), 0, stream,
                           bufa, stats2, g_out + (size_t)l * EMB, be_out + (size_t)l * EMB,
                           h, hout, invN, N * 16);
    }
}

// Round 2
// 745.753 us; speedup vs baseline: 1.7803x; 1.7803x over previous
//
#include <hip/hip_runtime.h>
#include <stdint.h>

#define EMB 64
#define BN_EPS 1e-5f

// ---------------- zero init (ws is poisoned 0xAA every call) ----------------
__global__ void k_zero(int* __restrict__ counts, float* __restrict__ stats,
                       int n, int nstats) {
    int i = blockIdx.x * blockDim.x + threadIdx.x;
    if (i < n) counts[i] = 0;
    if (i < nstats) stats[i] = 0.0f;
}

// ---------------- CSR build ----------------
__global__ void k_hist(const int* __restrict__ ei, int* __restrict__ counts, int E) {
    int stride = gridDim.x * blockDim.x;
    for (int e = blockIdx.x * blockDim.x + threadIdx.x; e < E; e += stride) {
        atomicAdd(&counts[ei[E + e]], 1);   // dst row
    }
}

__global__ void k_scanA(const int* __restrict__ counts, int* __restrict__ bsum, int n) {
    __shared__ int a[256];
    int t = threadIdx.x;
    int i = blockIdx.x * 256 + t;
    a[t] = (i < n) ? counts[i] : 0;
    __syncthreads();
    for (int off = 128; off >= 1; off >>= 1) {
        if (t < off) a[t] += a[t + off];
        __syncthreads();
    }
    if (t == 0) bsum[blockIdx.x] = a[0];
}

__global__ void k_scanB(int* __restrict__ bsum, int nb) {
    __shared__ int a[256];
    __shared__ int carry;
    int t = threadIdx.x;
    if (t == 0) carry = 0;
    __syncthreads();
    for (int base = 0; base < nb; base += 256) {
        int v = (base + t < nb) ? bsum[base + t] : 0;
        a[t] = v;
        __syncthreads();
        for (int off = 1; off < 256; off <<= 1) {
            int x = (t >= off) ? a[t - off] : 0;
            __syncthreads();
            a[t] += x;
            __syncthreads();
        }
        int excl = carry + (t ? a[t - 1] : 0);
        int tot  = carry + a[255];
        if (base + t < nb) bsum[base + t] = excl;   // in place: becomes block offsets
        __syncthreads();
        if (t == 0) carry = tot;
        __syncthreads();
    }
}

__global__ void k_scanC(const int* __restrict__ counts, const int* __restrict__ boff,
                        int* __restrict__ rowst, int* __restrict__ cursor, int n) {
    __shared__ int a[256];
    int t = threadIdx.x;
    int i = blockIdx.x * 256 + t;
    int v = (i < n) ? counts[i] : 0;
    a[t] = v;
    __syncthreads();
    for (int off = 1; off < 256; off <<= 1) {
        int x = (t >= off) ? a[t - off] : 0;
        __syncthreads();
        a[t] += x;
        __syncthreads();
    }
    int excl = boff[blockIdx.x] + (t ? a[t - 1] : 0);
    if (i < n) { rowst[i] = excl; cursor[i] = excl; }
}

__global__ void k_scatter(const int* __restrict__ ei, const float* __restrict__ ew,
                          int* __restrict__ cursor, int2* __restrict__ pairs, int E) {
    int stride = gridDim.x * blockDim.x;
    for (int e = blockIdx.x * blockDim.x + threadIdx.x; e < E; e += stride) {
        int d = ei[E + e];
        int pos = atomicAdd(&cursor[d], 1);
        pairs[pos] = make_int2(ei[e], __float_as_int(ew[e]));
    }
}

// ---------------- aggregation: wave-per-node, lane=feature ----------------
__global__ void k_agg(const float* __restrict__ h, const int* __restrict__ rowst,
                      const int* __restrict__ counts, const int2* __restrict__ pairs,
                      float* __restrict__ out, int N) {
    const int lane = threadIdx.x & 63;
    int wave = (blockIdx.x * blockDim.x + threadIdx.x) >> 6;
    const int nwaves = (gridDim.x * blockDim.x) >> 6;
    for (int node = wave; node < N; node += nwaves) {
        int un = __builtin_amdgcn_readfirstlane(node);
        int s = rowst[un];
        int c = counts[un];
        int end = s + c;
        float a0 = 0.f, a1 = 0.f, a2 = 0.f, a3 = 0.f;
        int e = s;
        for (; e + 3 < end; e += 4) {
            int2 p0 = pairs[e];
            int2 p1 = pairs[e + 1];
            int2 p2 = pairs[e + 2];
            int2 p3 = pairs[e + 3];
            float v0 = h[(size_t)p0.x * EMB + lane];
            float v1 = h[(size_t)p1.x * EMB + lane];
            float v2 = h[(size_t)p2.x * EMB + lane];
            float v3 = h[(size_t)p3.x * EMB + lane];
            a0 = fmaf(__int_as_float(p0.y), v0, a0);
            a1 = fmaf(__int_as_float(p1.y), v1, a1);
            a2 = fmaf(__int_as_float(p2.y), v2, a2);
            a3 = fmaf(__int_as_float(p3.y), v3, a3);
        }
        for (; e < end; e++) {
            int2 p0 = pairs[e];
            a0 = fmaf(__int_as_float(p0.y), h[(size_t)p0.x * EMB + lane], a0);
        }
        out[(size_t)un * EMB + lane] = ((a0 + a1) + (a2 + a3)) + h[(size_t)un * EMB + lane];
    }
}

// ---------------- matmul: wave = 64 nodes x all 64 cols -------------------
// Results staged in padded LDS (stride 65) then flushed with fully-coalesced
// float4 stores (consecutive lanes -> consecutive 16B; full 128B lines, no RFO).
// BN_IN: apply batchnorm(stats)+relu to the input row before the matmul.
#define TB_STRIDE 65
template <bool BN_IN>
__global__ void __launch_bounds__(128) k_mm(
                     const float* __restrict__ in, const float* __restrict__ W,
                     const float* __restrict__ bias, const float* __restrict__ stats,
                     const float* __restrict__ g, const float* __restrict__ be,
                     float invN, float* __restrict__ out, int N) {
    __shared__ float tilebuf[2][64 * TB_STRIDE];
    const int lane = threadIdx.x & 63;
    float* tb = tilebuf[threadIdx.x >> 6];
    int wv = (blockIdx.x * blockDim.x + threadIdx.x) >> 6;
    const int nwv = (gridDim.x * blockDim.x) >> 6;
    const int ntiles = (N + 63) >> 6;
    for (int tile = wv; tile < ntiles; tile += nwv) {
        int utile = __builtin_amdgcn_readfirstlane(tile);
        int node = utile * 64 + lane;
        bool valid = node < N;

        float row[EMB];
        if (valid) {
            const float4* in4 = (const float4*)(in + (size_t)node * EMB);
#pragma unroll
            for (int i = 0; i < 16; i++) {
                float4 v = in4[i];
                row[4 * i + 0] = v.x; row[4 * i + 1] = v.y;
                row[4 * i + 2] = v.z; row[4 * i + 3] = v.w;
            }
        } else {
#pragma unroll
            for (int i = 0; i < EMB; i++) row[i] = 0.f;
        }

        if (BN_IN) {
#pragma unroll
            for (int f = 0; f < EMB; f++) {
                float m  = stats[f] * invN;
                float va = fmaf(stats[EMB + f], invN, -m * m);
                float rs = rsqrtf(va + BN_EPS);
                float sc = rs * g[f];
                float sh = fmaf(-m, sc, be[f]);
                row[f] = fmaxf(0.f, fmaf(row[f], sc, sh));
            }
        }

        for (int jc = 0; jc < 8; jc++) {
            int j0 = jc * 8;   // uniform
            float acc[8];
#pragma unroll
            for (int k = 0; k < 8; k++) acc[k] = bias[j0 + k];
#pragma unroll
            for (int f = 0; f < EMB; f++) {
                const float* wr = W + f * EMB + j0;   // uniform -> s_load
#pragma unroll
                for (int k = 0; k < 8; k++) acc[k] = fmaf(row[f], wr[k], acc[k]);
            }
#pragma unroll
            for (int k = 0; k < 8; k++) tb[lane * TB_STRIDE + j0 + k] = acc[k];
        }

        // flush: 16 fully-coalesced float4 stores per wave (4096 floats)
        const int tbase = utile * 64;
        float4* out4 = (float4*)out + (size_t)tbase * 16;   // 16 float4 per row
#pragma unroll
        for (int it = 0; it < 16; it++) {
            int flat4 = it * 64 + lane;      // float4 index within tile
            int nsub = flat4 >> 4;
            int c4 = flat4 & 15;
            if (tbase + nsub < N) {
                const float* s4 = tb + nsub * TB_STRIDE + c4 * 4;
                out4[flat4] = make_float4(s4[0], s4[1], s4[2], s4[3]);
            }
        }
    }
}

// ---------------- per-feature sum / sumsq ----------------
__global__ void k_stats(const float* __restrict__ in, float* __restrict__ st, int total) {
    float s = 0.f, q = 0.f;
    int stride = gridDim.x * blockDim.x;
    for (int i = blockIdx.x * blockDim.x + threadIdx.x; i < total; i += stride) {
        float v = in[i];
        s += v;
        q = fmaf(v, v, q);
    }
    __shared__ float rs[256], rq[256];
    rs[threadIdx.x] = s; rq[threadIdx.x] = q;
    __syncthreads();
    if (threadIdx.x < 64) {
#pragma unroll
        for (int w = 64; w < 256; w += 64) {
            s += rs[threadIdx.x + w];
            q += rq[threadIdx.x + w];
        }
        atomicAdd(&st[threadIdx.x], s);
        atomicAdd(&st[EMB + threadIdx.x], q);
    }
}

// ---------------- outer BN + relu + residual ----------------
__global__ void k_bnres(const float* __restrict__ u, const float* __restrict__ st,
                        const float* __restrict__ g, const float* __restrict__ be,
                        const float* __restrict__ hin, float* __restrict__ hout,
                        float invN, int total4) {
    int stride = gridDim.x * blockDim.x;
    for (int i4 = blockIdx.x * blockDim.x + threadIdx.x; i4 < total4; i4 += stride) {
        int c = i4 & 15;  // which float4-chunk of the 64-feature row
        float4 uv = ((const float4*)u)[i4];
        float4 hv = ((const float4*)hin)[i4];
        float4 sv = ((const float4*)st)[c];
        float4 qv = ((const float4*)(st + EMB))[c];
        float4 gv = ((const float4*)g)[c];
        float4 bv = ((const float4*)be)[c];
        float4 o;
#define BNR(comp)                                                     \
        {                                                             \
            float m  = sv.comp * invN;                                \
            float va = fmaf(qv.comp, invN, -m * m);                   \
            float rs = rsqrtf(va + BN_EPS);                           \
            float sc = rs * gv.comp;                                  \
            float sh = fmaf(-m, sc, bv.comp);                         \
            float r  = fmaxf(0.f, fmaf(uv.comp, sc, sh));             \
            o.comp = r + hv.comp;                                     \
        }
        BNR(x) BNR(y) BNR(z) BNR(w)
#undef BNR
        ((float4*)hout)[i4] = o;
    }
}

// ---------------- launcher ----------------
extern "C" void kernel_launch(void* const* d_in, const int* in_sizes, int n_in,
                              void* d_out, int out_size, void* d_ws, size_t ws_size,
                              hipStream_t stream) {
    const float* x     = (const float*)d_in[0];
    const int*   ei    = (const int*)d_in[1];
    const float* ew    = (const float*)d_in[3];
    const float* ae_w  = (const float*)d_in[4];
    const float* ae_b  = (const float*)d_in[5];
    const float* W1    = (const float*)d_in[6];
    const float* b1    = (const float*)d_in[7];
    const float* g1    = (const float*)d_in[8];
    const float* be1   = (const float*)d_in[9];
    const float* W2    = (const float*)d_in[10];
    const float* b2    = (const float*)d_in[11];
    const float* g_out = (const float*)d_in[12];
    const float* be_out= (const float*)d_in[13];

    const int N = in_sizes[0] / EMB;      // x is [N,1,64]
    const int E = in_sizes[3];            // edge_weight [E]
    const int L = in_sizes[6] / (EMB * EMB);
    const float invN = 1.0f / (float)N;

    // workspace carve (256B aligned)
    uintptr_t p = (uintptr_t)d_ws;
    auto alloc = [&](size_t bytes) -> void* {
        p = (p + 255) & ~(uintptr_t)255;
        void* r = (void*)p;
        p += bytes;
        return r;
    };
    float* h     = (float*)alloc((size_t)N * EMB * 4);
    float* bufa  = (float*)alloc((size_t)N * EMB * 4);  // agg output, then reused as u
    float* buft  = (float*)alloc((size_t)N * EMB * 4);  // t
    int*   counts= (int*)alloc((size_t)N * 4);
    int*   rowst = (int*)alloc((size_t)N * 4);
    int*   cursor= (int*)alloc((size_t)N * 4);
    const int NB = (N + 255) / 256;
    int*   bsum  = (int*)alloc((size_t)NB * 4);
    int2*  pairs = (int2*)alloc((size_t)E * 8);
    float* stats = (float*)alloc((size_t)L * 2 * 2 * EMB * 4);
    (void)ws_size; (void)n_in; (void)out_size;

    const int nstats = L * 2 * 2 * EMB;
    int zgrid = ((N > nstats ? N : nstats) + 255) / 256;
    hipLaunchKernelGGL(k_zero, dim3(zgrid), dim3(256), 0, stream, counts, stats, N, nstats);

    // encoder: h = x @ ae_w + ae_b
    const int ntiles = (N + 63) / 64;
    const int mmgrid = (ntiles + 1) / 2;   // 2 waves / block (32.5KB LDS each)
    hipLaunchKernelGGL(k_mm<false>, dim3(mmgrid), dim3(128), 0, stream,
                       x, ae_w, ae_b, (const float*)nullptr, (const float*)nullptr,
                       (const float*)nullptr, 0.f, h, N);

    // CSR build
    const int eg = (E + 255) / 256;
    hipLaunchKernelGGL(k_hist,  dim3(eg), dim3(256), 0, stream, ei, counts, E);
    hipLaunchKernelGGL(k_scanA, dim3(NB), dim3(256), 0, stream, counts, bsum, N);
    hipLaunchKernelGGL(k_scanB, dim3(1),  dim3(256), 0, stream, bsum, NB);
    hipLaunchKernelGGL(k_scanC, dim3(NB), dim3(256), 0, stream, counts, bsum, rowst, cursor, N);
    hipLaunchKernelGGL(k_scatter, dim3(eg), dim3(256), 0, stream, ei, ew, cursor, pairs, E);

    for (int l = 0; l < L; l++) {
        const float* stats1 = stats + (size_t)(l * 2 + 0) * 2 * EMB;
        const float* stats2 = stats + (size_t)(l * 2 + 1) * 2 * EMB;

        // agg + self
        hipLaunchKernelGGL(k_agg, dim3(1024), dim3(256), 0, stream,
                           h, rowst, counts, pairs, bufa, N);
        // t = (agg) @ W1 + b1
        hipLaunchKernelGGL(k_mm<false>, dim3(mmgrid), dim3(128), 0, stream,
                           bufa, W1 + (size_t)l * EMB * EMB, b1 + (size_t)l * EMB,
                           (const float*)nullptr, (const float*)nullptr,
                           (const float*)nullptr, 0.f, buft, N);
        // stats of t
        hipLaunchKernelGGL(k_stats, dim3(256), dim3(256), 0, stream,
                           buft, (float*)stats1, N * EMB);
        // u = relu(bn(t)) @ W2 + b2     (bufa reused as u)
        hipLaunchKernelGGL(k_mm<true>, dim3(mmgrid), dim3(128), 0, stream,
                           buft, W2 + (size_t)l * EMB * EMB, b2 + (size_t)l * EMB,
                           stats1, g1 + (size_t)l * EMB, be1 + (size_t)l * EMB,
                           invN, bufa, N);
        // stats of u
        hipLaunchKernelGGL(k_stats, dim3(256), dim3(256), 0, stream,
                           bufa, (float*)stats2, N * EMB);
        // h = relu(bn(u)) + h   (last layer writes d_out)
        float* hout = (l == L - 1) ? (float*)d_out : h;
        hipLaunchKernelGGL(k_bnres, dim3(1024), dim3(256), 0, stream,
                           bufa, stats2, g_out + (size_t)l * EMB, be_out + (size_t)l * EMB,
                           h, hout, invN, N * 16);
    }
}